// Round 1
// baseline (3277.427 us; speedup 1.0000x reference)
//
#include <hip/hip_runtime.h>
#include <math.h>

#define B_ 2
#define S_ 1024
#define H_ 1024
#define NH_ 16
#define D_ 64
#define VOCAB 129   // 2*64+1

// ---------------------------------------------------------------------------
// Build the sinusoid table tab[VOCAB][D]: tab[r][2p] = sin(r*div_p),
// tab[r][2p+1] = cos(r*div_p), div_p = exp(-(2p)*ln(10000)/D)
// ---------------------------------------------------------------------------
__global__ void build_tab_kernel(float* __restrict__ tab) {
    int r = blockIdx.x;       // 0..128
    int d = threadIdx.x;      // 0..63
    int p = d >> 1;
    float div = __expf((float)(2 * p) * (-logf(10000.0f) / (float)D_));
    float ang = (float)r * div;
    tab[r * D_ + d] = (d & 1) ? cosf(ang) : sinf(ang);
}

// ---------------------------------------------------------------------------
// C[m,o] = sum_k A[m,k] * W[o,k] + bias[o], stored into [B,NH,S,D] layout:
// out[((b*NH + o/64)*S + s)*64 + o%64], with m = b*S + s.
// 64x64 tile per block, 256 threads, 4x4 micro-tile, K-tile 16.
// ---------------------------------------------------------------------------
__global__ __launch_bounds__(256) void proj_gemm_kernel(
        const float* __restrict__ A, const float* __restrict__ W,
        const float* __restrict__ bias, float* __restrict__ out) {
    __shared__ float As[64][17];
    __shared__ float Ws[64][17];
    const int tid = threadIdx.x;
    const int tx = tid & 15, ty = tid >> 4;
    const int m0 = blockIdx.y * 64, n0 = blockIdx.x * 64;
    const int lr = tid >> 2;            // 0..63  (row within tile to load)
    const int lc = (tid & 3) * 4;       // 0,4,8,12 (col group)

    float c[4][4] = {};

    for (int kt = 0; kt < H_; kt += 16) {
        float4 av = *(const float4*)&A[(size_t)(m0 + lr) * H_ + kt + lc];
        float4 wv = *(const float4*)&W[(size_t)(n0 + lr) * H_ + kt + lc];
        As[lr][lc + 0] = av.x; As[lr][lc + 1] = av.y;
        As[lr][lc + 2] = av.z; As[lr][lc + 3] = av.w;
        Ws[lr][lc + 0] = wv.x; Ws[lr][lc + 1] = wv.y;
        Ws[lr][lc + 2] = wv.z; Ws[lr][lc + 3] = wv.w;
        __syncthreads();
#pragma unroll
        for (int kk = 0; kk < 16; kk++) {
            float a0 = As[ty * 4 + 0][kk], a1 = As[ty * 4 + 1][kk];
            float a2 = As[ty * 4 + 2][kk], a3 = As[ty * 4 + 3][kk];
            float b0 = Ws[tx * 4 + 0][kk], b1 = Ws[tx * 4 + 1][kk];
            float b2 = Ws[tx * 4 + 2][kk], b3 = Ws[tx * 4 + 3][kk];
            c[0][0] += a0 * b0; c[0][1] += a0 * b1; c[0][2] += a0 * b2; c[0][3] += a0 * b3;
            c[1][0] += a1 * b0; c[1][1] += a1 * b1; c[1][2] += a1 * b2; c[1][3] += a1 * b3;
            c[2][0] += a2 * b0; c[2][1] += a2 * b1; c[2][2] += a2 * b2; c[2][3] += a2 * b3;
            c[3][0] += a3 * b0; c[3][1] += a3 * b1; c[3][2] += a3 * b2; c[3][3] += a3 * b3;
        }
        __syncthreads();
    }

#pragma unroll
    for (int i = 0; i < 4; i++) {
#pragma unroll
        for (int j = 0; j < 4; j++) {
            int m = m0 + ty * 4 + i;
            int o = n0 + tx * 4 + j;
            int bb = m >> 10, ss = m & 1023;
            int nn = o >> 6, dd = o & 63;
            out[(size_t)(((bb * NH_ + nn) << 10) + ss) * D_ + dd] = c[i][j] + bias[o];
        }
    }
}

// ---------------------------------------------------------------------------
// Attention: one block per (query i, head n, batch b). 256 threads.
// ---------------------------------------------------------------------------
__device__ __forceinline__ float block_reduce_sum(float val, float* red, int tid) {
    red[tid] = val;
    __syncthreads();
    for (int st = 128; st > 0; st >>= 1) {
        if (tid < st) red[tid] += red[tid + st];
        __syncthreads();
    }
    float r = red[0];
    __syncthreads();
    return r;
}

__device__ __forceinline__ float block_reduce_max(float val, float* red, int tid) {
    red[tid] = val;
    __syncthreads();
    for (int st = 128; st > 0; st >>= 1) {
        if (tid < st) red[tid] = fmaxf(red[tid], red[tid + st]);
        __syncthreads();
    }
    float r = red[0];
    __syncthreads();
    return r;
}

__global__ __launch_bounds__(256) void attn_kernel(
        const float* __restrict__ q, const float* __restrict__ k,
        const float* __restrict__ v, const float* __restrict__ tab,
        const float* __restrict__ mask, float* __restrict__ out) {
    const int i = blockIdx.x;   // query
    const int n = blockIdx.y;   // head
    const int b = blockIdx.z;   // batch
    const int tid = threadIdx.x;

    __shared__ float qs[D_];
    __shared__ float qrel[VOCAB];
    __shared__ float sc[S_];
    __shared__ float Pb[VOCAB];
    __shared__ float red[256];

    const size_t head_off = (size_t)(b * NH_ + n) * S_ * D_;
    const float* qrow = q + head_off + (size_t)i * D_;
    const float* kbase = k + head_off;
    const float* vbase = v + head_off;

    if (tid < D_) qs[tid] = qrow[tid];
    __syncthreads();

    // per-query relative-position scores for all 129 buckets
    if (tid < VOCAB) {
        float s = 0.f;
#pragma unroll 8
        for (int d = 0; d < D_; d++) s += qs[d] * tab[tid * D_ + d];
        qrel[tid] = s;
    }
    __syncthreads();

    // scores
    const float4* q4 = (const float4*)qs;
    for (int j = tid; j < S_; j += 256) {
        const float4* kr = (const float4*)(kbase + (size_t)j * D_);
        float s = 0.f;
#pragma unroll
        for (int d4 = 0; d4 < D_ / 4; d4++) {
            float4 kkv = kr[d4];
            float4 qq = q4[d4];
            s += qq.x * kkv.x + qq.y * kkv.y + qq.z * kkv.z + qq.w * kkv.w;
        }
        int off = j - i;
        off = off < -64 ? -64 : (off > 64 ? 64 : off);
        s += qrel[off + 64];
        s = s * 0.125f + mask[b * S_ + j];
        sc[j] = s;
    }
    __syncthreads();

    // softmax (stable)
    float lm = -INFINITY;
    for (int j = tid; j < S_; j += 256) lm = fmaxf(lm, sc[j]);
    float mx = block_reduce_max(lm, red, tid);

    float ls = 0.f, llo = 0.f, lhi = 0.f;
    for (int j = tid; j < S_; j += 256) {
        float p = __expf(sc[j] - mx);
        sc[j] = p;
        ls += p;
        if (j - i <= -64) llo += p;   // bucket 0
        if (j - i >= 64) lhi += p;    // bucket 128
    }
    float denom = block_reduce_sum(ls, red, tid);
    float plo = block_reduce_sum(llo, red, tid);
    float phi = block_reduce_sum(lhi, red, tid);

    // bucket-aggregated probabilities
    if (tid == 0) { Pb[0] = plo; Pb[128] = phi; }
    if (tid >= 1 && tid <= 127) {
        int j = i + tid - 64;     // offset in (-64, 64)
        Pb[tid] = (j >= 0 && j < S_) ? sc[j] : 0.f;
    }
    __syncthreads();

    // context: probs @ V  +  bucketProbs @ tab, then normalize
    const int d = tid & 63, part = tid >> 6;
    float acc = 0.f;
    for (int j = part * 256; j < part * 256 + 256; j++)
        acc += sc[j] * vbase[(size_t)j * D_ + d];
    red[tid] = acc;
    __syncthreads();
    if (tid < D_) {
        float a = red[tid] + red[tid + 64] + red[tid + 128] + red[tid + 192];
        float rl = 0.f;
#pragma unroll 8
        for (int r = 0; r < VOCAB; r++) rl += Pb[r] * tab[r * D_ + tid];
        out[(size_t)(b * S_ + i) * H_ + n * D_ + tid] = (a + rl) / denom;
    }
}

// ---------------------------------------------------------------------------
extern "C" void kernel_launch(void* const* d_in, const int* in_sizes, int n_in,
                              void* d_out, int out_size, void* d_ws, size_t ws_size,
                              hipStream_t stream) {
    const float* hidden = (const float*)d_in[0];
    const float* mask   = (const float*)d_in[1];
    const float* Wq     = (const float*)d_in[2];
    const float* bq     = (const float*)d_in[3];
    const float* Wk     = (const float*)d_in[4];
    const float* bk     = (const float*)d_in[5];
    const float* Wv     = (const float*)d_in[6];
    const float* bv     = (const float*)d_in[7];
    float* out = (float*)d_out;
    float* ws  = (float*)d_ws;

    const size_t QKV = (size_t)B_ * NH_ * S_ * D_;   // 2M floats
    float* q   = ws;
    float* kk  = ws + QKV;
    float* vv  = ws + 2 * QKV;
    float* tab = ws + 3 * QKV;

    build_tab_kernel<<<dim3(VOCAB), dim3(D_), 0, stream>>>(tab);

    dim3 pg(H_ / 64, (B_ * S_) / 64), pb(256);
    proj_gemm_kernel<<<pg, pb, 0, stream>>>(hidden, Wq, bq, q);
    proj_gemm_kernel<<<pg, pb, 0, stream>>>(hidden, Wk, bk, kk);
    proj_gemm_kernel<<<pg, pb, 0, stream>>>(hidden, Wv, bv, vv);

    attn_kernel<<<dim3(S_, NH_, B_), dim3(256), 0, stream>>>(q, kk, vv, tab, mask, out);
}

// Round 2
// 540.536 us; speedup vs baseline: 6.0633x; 6.0633x over previous
//
#include <hip/hip_runtime.h>
#include <hip/hip_bf16.h>
#include <math.h>

#define B_ 2
#define S_ 1024
#define H_ 1024
#define NH_ 16
#define D_ 64
#define VOCAB 129
#define TQ 32
#define TK 64
#define LSTR 68    // LDS row stride for 64-wide tiles (float4-aligned, 2-way bank alias = free)
#define RSTR 132   // qrel / Pb row stride

__device__ __forceinline__ float dot4(float4 a, float4 b) {
    return a.x * b.x + a.y * b.y + a.z * b.z + a.w * b.w;
}

#define FMA4(O, s, V) { O.x += (s)*V.x; O.y += (s)*V.y; O.z += (s)*V.z; O.w += (s)*V.w; }

// ---------------------------------------------------------------------------
__global__ void build_tab_kernel(float* __restrict__ tab) {
    int r = blockIdx.x;       // 0..128
    int d = threadIdx.x;      // 0..63
    int p = d >> 1;
    float div = __expf((float)(2 * p) * (-logf(10000.0f) / (float)D_));
    float ang = (float)r * div;
    tab[r * D_ + d] = (d & 1) ? cosf(ang) : sinf(ang);
}

// ---------------------------------------------------------------------------
// C[m,o] = sum_k A[m,k] * W[o,k] + bias[o] -> [B,NH,S,D] layout.
// 64x64 tile, K-step 64, 256 threads, 4x4 micro-tile, float4 LDS reads.
// ---------------------------------------------------------------------------
__global__ __launch_bounds__(256) void proj_gemm_kernel(
        const float* __restrict__ A, const float* __restrict__ W,
        const float* __restrict__ bias, float* __restrict__ out) {
    __shared__ __align__(16) float As[64 * LSTR];
    __shared__ __align__(16) float Ws[64 * LSTR];
    const int tid = threadIdx.x;
    const int tx = tid & 15, ty = tid >> 4;
    const int n0 = blockIdx.x * 64, m0 = blockIdx.y * 64;

    float acc[4][4] = {};

    for (int kt = 0; kt < H_; kt += 64) {
#pragma unroll
        for (int t = 0; t < 4; t++) {
            int idx = tid + t * 256;
            int row = idx >> 4, c4 = (idx & 15) << 2;
            *(float4*)&As[row * LSTR + c4] = *(const float4*)&A[(size_t)(m0 + row) * H_ + kt + c4];
            *(float4*)&Ws[row * LSTR + c4] = *(const float4*)&W[(size_t)(n0 + row) * H_ + kt + c4];
        }
        __syncthreads();
#pragma unroll 2
        for (int kk = 0; kk < 64; kk += 4) {
            float4 bv[4], av[4];
#pragma unroll
            for (int jj = 0; jj < 4; jj++) bv[jj] = *(const float4*)&Ws[(tx + 16 * jj) * LSTR + kk];
#pragma unroll
            for (int ii = 0; ii < 4; ii++) {
                av[ii] = *(const float4*)&As[(ty + 16 * ii) * LSTR + kk];
#pragma unroll
                for (int jj = 0; jj < 4; jj++) acc[ii][jj] += dot4(av[ii], bv[jj]);
            }
        }
        __syncthreads();
    }

#pragma unroll
    for (int ii = 0; ii < 4; ii++) {
#pragma unroll
        for (int jj = 0; jj < 4; jj++) {
            int m = m0 + ty + 16 * ii;
            int o = n0 + tx + 16 * jj;
            out[(size_t)(((m >> 10) * NH_ + (o >> 6)) * S_ + (m & 1023)) * D_ + (o & 63)] =
                acc[ii][jj] + bias[o];
        }
    }
}

// ---------------------------------------------------------------------------
// Attention: one block = 32 queries of one (b, head). 256 threads (16x16).
// Unnormalized softmax (no max subtraction; scores bounded ~|s|<15).
// Rel-pos key term via qrel[i][bucket]; rel-pos value term via bf16 bucket
// probs (middle) + fp32 tail scalars.
// ---------------------------------------------------------------------------
__global__ __launch_bounds__(256) void attn_kernel(
        const float* __restrict__ q, const float* __restrict__ k,
        const float* __restrict__ v, const float* __restrict__ tab,
        const float* __restrict__ mask, float* __restrict__ out) {
    __shared__ __align__(16) float Qs[TQ * LSTR];          //  8.7 KB
    __shared__ __align__(16) float KV[TK * LSTR];          // 17.4 KB (K then V)
    __shared__ __align__(16) float Ps[TQ * LSTR];          //  8.7 KB
    __shared__ float Qr[TQ * RSTR];                        // 16.9 KB
    __shared__ __hip_bfloat16 Pb[TQ * RSTR];               //  8.4 KB

    const int tid = threadIdx.x;
    const int tx = tid & 15, ty = tid >> 4;
    const int q0 = blockIdx.x * TQ;
    const int n = blockIdx.y, b = blockIdx.z;
    const size_t head = (size_t)(b * NH_ + n) * S_ * D_;

    // zero middle-bucket probs
    for (int e = tid; e < TQ * RSTR; e += 256) Pb[e] = __float2bfloat16(0.0f);

    // stage Q tile
#pragma unroll
    for (int t = 0; t < 2; t++) {
        int idx = tid + t * 256;
        int row = idx >> 4, c4 = (idx & 15) << 2;
        *(float4*)&Qs[row * LSTR + c4] = *(const float4*)&q[head + (size_t)(q0 + row) * D_ + c4];
    }
    __syncthreads();

    // qrel[i][r] = q_i . tab[r],  r in [0,129): two staged GEMM passes + r=128
    for (int pass = 0; pass < 2; pass++) {
#pragma unroll
        for (int t = 0; t < 4; t++) {
            int idx = tid + t * 256;
            int row = idx >> 4, c4 = (idx & 15) << 2;
            *(float4*)&KV[row * LSTR + c4] = *(const float4*)&tab[(size_t)(pass * 64 + row) * D_ + c4];
        }
        __syncthreads();
        float acc[2][4] = {};
#pragma unroll 2
        for (int kk = 0; kk < D_; kk += 4) {
            float4 a0 = *(const float4*)&Qs[ty * LSTR + kk];
            float4 a1 = *(const float4*)&Qs[(ty + 16) * LSTR + kk];
#pragma unroll
            for (int jj = 0; jj < 4; jj++) {
                float4 bv = *(const float4*)&KV[(tx + 16 * jj) * LSTR + kk];
                acc[0][jj] += dot4(a0, bv);
                acc[1][jj] += dot4(a1, bv);
            }
        }
#pragma unroll
        for (int jj = 0; jj < 4; jj++) {
            Qr[ty * RSTR + pass * 64 + tx + 16 * jj] = acc[0][jj];
            Qr[(ty + 16) * RSTR + pass * 64 + tx + 16 * jj] = acc[1][jj];
        }
        __syncthreads();
    }
    if (tid < TQ) {
        float s = 0.f;
#pragma unroll 8
        for (int d = 0; d < D_; d++) s += Qs[tid * LSTR + d] * tab[128 * D_ + d];
        Qr[tid * RSTR + 128] = s;
    }
    __syncthreads();

    float4 O0 = {0.f, 0.f, 0.f, 0.f}, O1 = {0.f, 0.f, 0.f, 0.f};
    float lsum0 = 0.f, lsum1 = 0.f, plo0 = 0.f, plo1 = 0.f, phi0 = 0.f, phi1 = 0.f;
    const int gi0 = q0 + ty, gi1 = q0 + ty + 16;

    for (int kt = 0; kt < S_ / TK; kt++) {
        const int k0 = kt * TK;
        // stage K
#pragma unroll
        for (int t = 0; t < 4; t++) {
            int idx = tid + t * 256;
            int row = idx >> 4, c4 = (idx & 15) << 2;
            *(float4*)&KV[row * LSTR + c4] = *(const float4*)&k[head + (size_t)(k0 + row) * D_ + c4];
        }
        __syncthreads();

        // S = Q K^T  (2x4 micro)
        float s[2][4] = {};
#pragma unroll 2
        for (int kk = 0; kk < D_; kk += 4) {
            float4 a0 = *(const float4*)&Qs[ty * LSTR + kk];
            float4 a1 = *(const float4*)&Qs[(ty + 16) * LSTR + kk];
#pragma unroll
            for (int jj = 0; jj < 4; jj++) {
                float4 bv = *(const float4*)&KV[(tx + 16 * jj) * LSTR + kk];
                s[0][jj] += dot4(a0, bv);
                s[1][jj] += dot4(a1, bv);
            }
        }

        // rel-score add, exp, bucket bookkeeping, store P
#pragma unroll
        for (int jj = 0; jj < 4; jj++) {
            int j = tx + 16 * jj;
            int gj = k0 + j;
            float mj = mask[b * S_ + gj];
#pragma unroll
            for (int ii = 0; ii < 2; ii++) {
                int i = ty + 16 * ii;
                int gi = ii ? gi1 : gi0;
                int off = gj - gi;
                int bk = off < -64 ? 0 : (off > 64 ? 128 : off + 64);
                float rel = Qr[i * RSTR + bk];
                float p = __expf((s[ii][jj] + rel) * 0.125f + mj);
                if (ii) lsum1 += p; else lsum0 += p;
                if (bk == 0)        { if (ii) plo1 += p; else plo0 += p; }
                else if (bk == 128) { if (ii) phi1 += p; else phi0 += p; }
                else Pb[i * RSTR + bk] = __float2bfloat16(p);
                Ps[i * LSTR + j] = p;
            }
        }
        __syncthreads();   // K reads + P writes done

        // stage V (same buffer)
#pragma unroll
        for (int t = 0; t < 4; t++) {
            int idx = tid + t * 256;
            int row = idx >> 4, c4 = (idx & 15) << 2;
            *(float4*)&KV[row * LSTR + c4] = *(const float4*)&v[head + (size_t)(k0 + row) * D_ + c4];
        }
        __syncthreads();

        // O += P V   (rows i, dim-quad 4*tx)
#pragma unroll 2
        for (int jq = 0; jq < TK; jq += 4) {
            float4 p0 = *(const float4*)&Ps[ty * LSTR + jq];
            float4 p1 = *(const float4*)&Ps[(ty + 16) * LSTR + jq];
            float4 v0 = *(const float4*)&KV[(jq + 0) * LSTR + 4 * tx];
            float4 v1 = *(const float4*)&KV[(jq + 1) * LSTR + 4 * tx];
            float4 v2 = *(const float4*)&KV[(jq + 2) * LSTR + 4 * tx];
            float4 v3 = *(const float4*)&KV[(jq + 3) * LSTR + 4 * tx];
            FMA4(O0, p0.x, v0) FMA4(O0, p0.y, v1) FMA4(O0, p0.z, v2) FMA4(O0, p0.w, v3)
            FMA4(O1, p1.x, v0) FMA4(O1, p1.y, v1) FMA4(O1, p1.z, v2) FMA4(O1, p1.w, v3)
        }
        __syncthreads();   // V + P reads done before next tile
    }

    // reduce l / plo / phi across the 16 lanes sharing a query row
#pragma unroll
    for (int w = 1; w < 16; w <<= 1) {
        lsum0 += __shfl_xor(lsum0, w); lsum1 += __shfl_xor(lsum1, w);
        plo0  += __shfl_xor(plo0,  w); plo1  += __shfl_xor(plo1,  w);
        phi0  += __shfl_xor(phi0,  w); phi1  += __shfl_xor(phi1,  w);
    }

    // epilogue: rel-value term + tails, normalize, store
#pragma unroll
    for (int ii = 0; ii < 2; ii++) {
        int i = ty + 16 * ii;
        float4 O = ii ? O1 : O0;
        float ls = ii ? lsum1 : lsum0;
        float pl = ii ? plo1 : plo0;
        float ph = ii ? phi1 : phi0;
        float4 t0   = *(const float4*)&tab[0 * D_ + 4 * tx];
        float4 t128 = *(const float4*)&tab[128 * D_ + 4 * tx];
        FMA4(O, pl, t0) FMA4(O, ph, t128)
        for (int r = 1; r < 128; r++) {
            float pb = __bfloat162float(Pb[i * RSTR + r]);
            float4 tr = *(const float4*)&tab[r * D_ + 4 * tx];
            FMA4(O, pb, tr)
        }
        float inv = 1.0f / ls;
        O.x *= inv; O.y *= inv; O.z *= inv; O.w *= inv;
        int gi = q0 + i;
        *(float4*)&out[((size_t)(b * S_ + gi) * NH_ + n) * D_ + 4 * tx] = O;
    }
}

// ---------------------------------------------------------------------------
extern "C" void kernel_launch(void* const* d_in, const int* in_sizes, int n_in,
                              void* d_out, int out_size, void* d_ws, size_t ws_size,
                              hipStream_t stream) {
    const float* hidden = (const float*)d_in[0];
    const float* mask   = (const float*)d_in[1];
    const float* Wq     = (const float*)d_in[2];
    const float* bq     = (const float*)d_in[3];
    const float* Wk     = (const float*)d_in[4];
    const float* bk     = (const float*)d_in[5];
    const float* Wv     = (const float*)d_in[6];
    const float* bv     = (const float*)d_in[7];
    float* out = (float*)d_out;
    float* ws  = (float*)d_ws;

    const size_t QKV = (size_t)B_ * NH_ * S_ * D_;   // 2M floats
    float* q   = ws;
    float* kk  = ws + QKV;
    float* vv  = ws + 2 * QKV;
    float* tab = ws + 3 * QKV;

    build_tab_kernel<<<dim3(VOCAB), dim3(D_), 0, stream>>>(tab);

    dim3 pg(H_ / 64, (B_ * S_) / 64), pb(256);
    proj_gemm_kernel<<<pg, pb, 0, stream>>>(hidden, Wq, bq, q);
    proj_gemm_kernel<<<pg, pb, 0, stream>>>(hidden, Wk, bk, kk);
    proj_gemm_kernel<<<pg, pb, 0, stream>>>(hidden, Wv, bv, vv);

    attn_kernel<<<dim3(S_ / TQ, NH_, B_), dim3(256), 0, stream>>>(q, kk, vv, tab, mask, out);
}

// Round 3
// 344.292 us; speedup vs baseline: 9.5193x; 1.5700x over previous
//
#include <hip/hip_runtime.h>
#include <hip/hip_bf16.h>
#include <math.h>

#define B_ 2
#define S_ 1024
#define H_ 1024
#define NH_ 16
#define D_ 64
#define VOCAB 129
#define TQ 32
#define TK 64
#define LSTR 68    // LDS row stride for 64-wide fp32 tiles
#define RSTR 132   // qrel / Pb row stride

typedef __bf16 bf16_t;
typedef __bf16 bf16x8 __attribute__((ext_vector_type(8)));
typedef __bf16 bf16x4 __attribute__((ext_vector_type(4)));
typedef float f32x4 __attribute__((ext_vector_type(4)));

__device__ __forceinline__ float dot4(float4 a, float4 b) {
    return a.x * b.x + a.y * b.y + a.z * b.z + a.w * b.w;
}

#define FMA4(O, s, V) { O.x += (s)*V.x; O.y += (s)*V.y; O.z += (s)*V.z; O.w += (s)*V.w; }

// ---------------------------------------------------------------------------
__global__ void build_tab_kernel(float* __restrict__ tab) {
    int r = blockIdx.x;       // 0..128
    int d = threadIdx.x;      // 0..63
    int p = d >> 1;
    float div = __expf((float)(2 * p) * (-logf(10000.0f) / (float)D_));
    float ang = (float)r * div;
    tab[r * D_ + d] = (d & 1) ? cosf(ang) : sinf(ang);
}

// ---------------------------------------------------------------------------
__global__ __launch_bounds__(256) void cast_f32_bf16(const float* __restrict__ src,
                                                     bf16_t* __restrict__ dst, int n4) {
    int i = blockIdx.x * 256 + threadIdx.x;
    if (i < n4) {
        float4 v = ((const float4*)src)[i];
        bf16x4 o = {(bf16_t)v.x, (bf16_t)v.y, (bf16_t)v.z, (bf16_t)v.w};
        ((bf16x4*)dst)[i] = o;
    }
}

// ---------------------------------------------------------------------------
// Fused QKV projection: C[2048 x 3072] = hidden_bf16 . Wbf^T (+bias),
// scattered into q/k/v [B,NH,S,D] fp32. m97 pattern: 128x128 tile, BK=32,
// global_load_lds width 16, mfma_f32_16x16x32_bf16, 4 waves in 2x2.
// ---------------------------------------------------------------------------
__global__ __launch_bounds__(256) void proj_mfma_kernel(
        const bf16_t* __restrict__ Abf,   // [2048][1024]
        const bf16_t* __restrict__ Wbf,   // [3072][1024]  (Wq;Wk;Wv)
        const float* __restrict__ bq, const float* __restrict__ bk,
        const float* __restrict__ bv,
        float* __restrict__ q, float* __restrict__ k, float* __restrict__ v) {
    __shared__ __align__(16) bf16_t As[128 * 32];   // 8 KB
    __shared__ __align__(16) bf16_t Bs[128 * 32];   // 8 KB
    const int tid = threadIdx.x;
    const int w = tid >> 6, l = tid & 63;
    const int m0 = blockIdx.y * 128, n0 = blockIdx.x * 128;
    const int wm = w & 1, wn = w >> 1;

    f32x4 acc[4][4] = {};

    const int lrow = l >> 2;          // 0..15: row within 16-row chunk
    const int lcol = (l & 3) * 8;     // element col offset (16B granules)
    const int frow = l & 15;          // MFMA fragment row/col
    const int kq = (l >> 4) * 8;      // MFMA fragment k-offset

    for (int kt = 0; kt < H_; kt += 32) {
#pragma unroll
        for (int t = 0; t < 2; t++) {
            int row = w * 32 + t * 16;
            const bf16_t* ga = Abf + (size_t)(m0 + row + lrow) * H_ + kt + lcol;
            const bf16_t* gb = Wbf + (size_t)(n0 + row + lrow) * H_ + kt + lcol;
            __builtin_amdgcn_global_load_lds(
                (const __attribute__((address_space(1))) void*)ga,
                (__attribute__((address_space(3))) void*)&As[row * 32], 16, 0, 0);
            __builtin_amdgcn_global_load_lds(
                (const __attribute__((address_space(1))) void*)gb,
                (__attribute__((address_space(3))) void*)&Bs[row * 32], 16, 0, 0);
        }
        __syncthreads();

        bf16x8 af[4], bfr[4];
#pragma unroll
        for (int im = 0; im < 4; im++)
            af[im] = *(const bf16x8*)&As[(wm * 64 + im * 16 + frow) * 32 + kq];
#pragma unroll
        for (int in = 0; in < 4; in++)
            bfr[in] = *(const bf16x8*)&Bs[(wn * 64 + in * 16 + frow) * 32 + kq];
#pragma unroll
        for (int im = 0; im < 4; im++)
#pragma unroll
            for (int in = 0; in < 4; in++)
                acc[im][in] = __builtin_amdgcn_mfma_f32_16x16x32_bf16(
                    af[im], bfr[in], acc[im][in], 0, 0, 0);
        __syncthreads();
    }

    // epilogue: bias + scatter to q/k/v [B,NH,S,D]
    const int proj = n0 >> 10;  // whole 128-tile lies in one projection
    const float* bias = proj == 0 ? bq : (proj == 1 ? bk : bv);
    float* dst = proj == 0 ? q : (proj == 1 ? k : v);
    const int cn = l & 15, cr4 = (l >> 4) * 4;
#pragma unroll
    for (int im = 0; im < 4; im++) {
#pragma unroll
        for (int in = 0; in < 4; in++) {
            int gn = n0 + wn * 64 + in * 16 + cn;
            int o = gn & 1023;
            int nn = o >> 6, dd = o & 63;
            float bsv = bias[o];
#pragma unroll
            for (int vr = 0; vr < 4; vr++) {
                int gm = m0 + wm * 64 + im * 16 + cr4 + vr;
                int bb = gm >> 10, ss = gm & 1023;
                dst[(size_t)(((bb * NH_ + nn) << 10) + ss) * D_ + dd] =
                    acc[im][in][vr] + bsv;
            }
        }
    }
}

// ---------------------------------------------------------------------------
// Attention: one block = 32 queries of one (b, head). 256 threads (16x16).
// Unnormalized softmax (scores bounded, no max subtraction needed).
// ---------------------------------------------------------------------------
__global__ __launch_bounds__(256) void attn_kernel(
        const float* __restrict__ q, const float* __restrict__ k,
        const float* __restrict__ v, const float* __restrict__ tab,
        const float* __restrict__ mask, float* __restrict__ out) {
    __shared__ __align__(16) float Qs[TQ * LSTR];
    __shared__ __align__(16) float KV[TK * LSTR];
    __shared__ __align__(16) float Ps[TQ * LSTR];
    __shared__ float Qr[TQ * RSTR];
    __shared__ __hip_bfloat16 Pb[TQ * RSTR];

    const int tid = threadIdx.x;
    const int tx = tid & 15, ty = tid >> 4;
    const int q0 = blockIdx.x * TQ;
    const int n = blockIdx.y, b = blockIdx.z;
    const size_t head = (size_t)(b * NH_ + n) * S_ * D_;

    for (int e = tid; e < TQ * RSTR; e += 256) Pb[e] = __float2bfloat16(0.0f);

#pragma unroll
    for (int t = 0; t < 2; t++) {
        int idx = tid + t * 256;
        int row = idx >> 4, c4 = (idx & 15) << 2;
        *(float4*)&Qs[row * LSTR + c4] = *(const float4*)&q[head + (size_t)(q0 + row) * D_ + c4];
    }
    __syncthreads();

    for (int pass = 0; pass < 2; pass++) {
#pragma unroll
        for (int t = 0; t < 4; t++) {
            int idx = tid + t * 256;
            int row = idx >> 4, c4 = (idx & 15) << 2;
            *(float4*)&KV[row * LSTR + c4] = *(const float4*)&tab[(size_t)(pass * 64 + row) * D_ + c4];
        }
        __syncthreads();
        float acc[2][4] = {};
#pragma unroll 2
        for (int kk = 0; kk < D_; kk += 4) {
            float4 a0 = *(const float4*)&Qs[ty * LSTR + kk];
            float4 a1 = *(const float4*)&Qs[(ty + 16) * LSTR + kk];
#pragma unroll
            for (int jj = 0; jj < 4; jj++) {
                float4 bv = *(const float4*)&KV[(tx + 16 * jj) * LSTR + kk];
                acc[0][jj] += dot4(a0, bv);
                acc[1][jj] += dot4(a1, bv);
            }
        }
#pragma unroll
        for (int jj = 0; jj < 4; jj++) {
            Qr[ty * RSTR + pass * 64 + tx + 16 * jj] = acc[0][jj];
            Qr[(ty + 16) * RSTR + pass * 64 + tx + 16 * jj] = acc[1][jj];
        }
        __syncthreads();
    }
    if (tid < TQ) {
        float s = 0.f;
#pragma unroll 8
        for (int d = 0; d < D_; d++) s += Qs[tid * LSTR + d] * tab[128 * D_ + d];
        Qr[tid * RSTR + 128] = s;
    }
    __syncthreads();

    float4 O0 = {0.f, 0.f, 0.f, 0.f}, O1 = {0.f, 0.f, 0.f, 0.f};
    float lsum0 = 0.f, lsum1 = 0.f, plo0 = 0.f, plo1 = 0.f, phi0 = 0.f, phi1 = 0.f;
    const int gi0 = q0 + ty, gi1 = q0 + ty + 16;

    for (int kt = 0; kt < S_ / TK; kt++) {
        const int k0 = kt * TK;
#pragma unroll
        for (int t = 0; t < 4; t++) {
            int idx = tid + t * 256;
            int row = idx >> 4, c4 = (idx & 15) << 2;
            *(float4*)&KV[row * LSTR + c4] = *(const float4*)&k[head + (size_t)(k0 + row) * D_ + c4];
        }
        __syncthreads();

        float s[2][4] = {};
#pragma unroll 2
        for (int kk = 0; kk < D_; kk += 4) {
            float4 a0 = *(const float4*)&Qs[ty * LSTR + kk];
            float4 a1 = *(const float4*)&Qs[(ty + 16) * LSTR + kk];
#pragma unroll
            for (int jj = 0; jj < 4; jj++) {
                float4 bv = *(const float4*)&KV[(tx + 16 * jj) * LSTR + kk];
                s[0][jj] += dot4(a0, bv);
                s[1][jj] += dot4(a1, bv);
            }
        }

#pragma unroll
        for (int jj = 0; jj < 4; jj++) {
            int j = tx + 16 * jj;
            int gj = k0 + j;
            float mj = mask[b * S_ + gj];
#pragma unroll
            for (int ii = 0; ii < 2; ii++) {
                int i = ty + 16 * ii;
                int gi = ii ? gi1 : gi0;
                int off = gj - gi;
                int bk = off < -64 ? 0 : (off > 64 ? 128 : off + 64);
                float rel = Qr[i * RSTR + bk];
                float p = __expf((s[ii][jj] + rel) * 0.125f + mj);
                if (ii) lsum1 += p; else lsum0 += p;
                if (bk == 0)        { if (ii) plo1 += p; else plo0 += p; }
                else if (bk == 128) { if (ii) phi1 += p; else phi0 += p; }
                else Pb[i * RSTR + bk] = __float2bfloat16(p);
                Ps[i * LSTR + j] = p;
            }
        }
        __syncthreads();

#pragma unroll
        for (int t = 0; t < 4; t++) {
            int idx = tid + t * 256;
            int row = idx >> 4, c4 = (idx & 15) << 2;
            *(float4*)&KV[row * LSTR + c4] = *(const float4*)&v[head + (size_t)(k0 + row) * D_ + c4];
        }
        __syncthreads();

#pragma unroll 2
        for (int jq = 0; jq < TK; jq += 4) {
            float4 p0 = *(const float4*)&Ps[ty * LSTR + jq];
            float4 p1 = *(const float4*)&Ps[(ty + 16) * LSTR + jq];
            float4 v0 = *(const float4*)&KV[(jq + 0) * LSTR + 4 * tx];
            float4 v1 = *(const float4*)&KV[(jq + 1) * LSTR + 4 * tx];
            float4 v2 = *(const float4*)&KV[(jq + 2) * LSTR + 4 * tx];
            float4 v3 = *(const float4*)&KV[(jq + 3) * LSTR + 4 * tx];
            FMA4(O0, p0.x, v0) FMA4(O0, p0.y, v1) FMA4(O0, p0.z, v2) FMA4(O0, p0.w, v3)
            FMA4(O1, p1.x, v0) FMA4(O1, p1.y, v1) FMA4(O1, p1.z, v2) FMA4(O1, p1.w, v3)
        }
        __syncthreads();
    }

#pragma unroll
    for (int w = 1; w < 16; w <<= 1) {
        lsum0 += __shfl_xor(lsum0, w); lsum1 += __shfl_xor(lsum1, w);
        plo0  += __shfl_xor(plo0,  w); plo1  += __shfl_xor(plo1,  w);
        phi0  += __shfl_xor(phi0,  w); phi1  += __shfl_xor(phi1,  w);
    }

#pragma unroll
    for (int ii = 0; ii < 2; ii++) {
        int i = ty + 16 * ii;
        float4 O = ii ? O1 : O0;
        float ls = ii ? lsum1 : lsum0;
        float pl = ii ? plo1 : plo0;
        float ph = ii ? phi1 : phi0;
        float4 t0   = *(const float4*)&tab[0 * D_ + 4 * tx];
        float4 t128 = *(const float4*)&tab[128 * D_ + 4 * tx];
        FMA4(O, pl, t0) FMA4(O, ph, t128)
        for (int r = 1; r < 128; r++) {
            float pb = __bfloat162float(Pb[i * RSTR + r]);
            float4 tr = *(const float4*)&tab[r * D_ + 4 * tx];
            FMA4(O, pb, tr)
        }
        float inv = 1.0f / ls;
        O.x *= inv; O.y *= inv; O.z *= inv; O.w *= inv;
        int gi = q0 + i;
        *(float4*)&out[((size_t)(b * S_ + gi) * NH_ + n) * D_ + 4 * tx] = O;
    }
}

// ---------------------------------------------------------------------------
extern "C" void kernel_launch(void* const* d_in, const int* in_sizes, int n_in,
                              void* d_out, int out_size, void* d_ws, size_t ws_size,
                              hipStream_t stream) {
    const float* hidden = (const float*)d_in[0];
    const float* mask   = (const float*)d_in[1];
    const float* Wq     = (const float*)d_in[2];
    const float* bq     = (const float*)d_in[3];
    const float* Wk     = (const float*)d_in[4];
    const float* bk     = (const float*)d_in[5];
    const float* Wv     = (const float*)d_in[6];
    const float* bv     = (const float*)d_in[7];
    float* out = (float*)d_out;

    char* wsb = (char*)d_ws;
    float* q    = (float*)(wsb);                               // 8 MB
    float* kk   = (float*)(wsb + (8u << 20));                  // 8 MB
    float* vv   = (float*)(wsb + (16u << 20));                 // 8 MB
    float* tab  = (float*)(wsb + (24u << 20));                 // 33 KB
    bf16_t* hidbf = (bf16_t*)(wsb + (24u << 20) + (64u << 10)); // 4 MB
    bf16_t* wbf   = (bf16_t*)(wsb + (28u << 20) + (64u << 10)); // 6 MB

    const int NM = 1024 * 1024;  // one weight matrix

    build_tab_kernel<<<dim3(VOCAB), dim3(D_), 0, stream>>>(tab);
    cast_f32_bf16<<<dim3((2 * NM / 4) / 256), dim3(256), 0, stream>>>(hidden, hidbf, 2 * NM / 4);
    cast_f32_bf16<<<dim3((NM / 4) / 256), dim3(256), 0, stream>>>(Wq, wbf, NM / 4);
    cast_f32_bf16<<<dim3((NM / 4) / 256), dim3(256), 0, stream>>>(Wk, wbf + NM, NM / 4);
    cast_f32_bf16<<<dim3((NM / 4) / 256), dim3(256), 0, stream>>>(Wv, wbf + 2 * NM, NM / 4);

    proj_mfma_kernel<<<dim3(3072 / 128, 2048 / 128), dim3(256), 0, stream>>>(
        hidbf, wbf, bq, bk, bv, q, kk, vv);

    attn_kernel<<<dim3(S_ / TQ, NH_, B_), dim3(256), 0, stream>>>(q, kk, vv, tab, mask, out);
}

// Round 4
// 216.877 us; speedup vs baseline: 15.1119x; 1.5875x over previous
//
#include <hip/hip_runtime.h>
#include <hip/hip_bf16.h>
#include <math.h>

#define B_ 2
#define S_ 1024
#define H_ 1024
#define NH_ 16
#define D_ 64
#define VOCAB 129

#define PSTR 72     // P LDS row stride (bf16): 144B, 2-way bank alias (free), 16B aligned
#define QRSTR 136   // Qr/Pb LDS row stride (bf16): 272B, 16B aligned

typedef __bf16 bf16_t;
typedef __bf16 bf16x8 __attribute__((ext_vector_type(8)));
typedef __bf16 bf16x4 __attribute__((ext_vector_type(4)));
typedef float f32x4 __attribute__((ext_vector_type(4)));

#define MFMA16(a, b, c) __builtin_amdgcn_mfma_f32_16x16x32_bf16(a, b, c, 0, 0, 0)
#define LGKM_FENCE() __asm__ volatile("s_waitcnt lgkmcnt(0)" ::: "memory")

// ---------------------------------------------------------------------------
// tab f32 [129][64]; tab_bf [144][64] (rows>=129 zero); tabT_bf [64][128]
// (tabT[d][r] = tab[r][d] for r<128; r=128 handled separately via tails).
// ---------------------------------------------------------------------------
__global__ void build_tab_kernel(float* __restrict__ tab, bf16_t* __restrict__ tab_bf,
                                 bf16_t* __restrict__ tabT_bf) {
    int r = blockIdx.x;       // 0..143
    int d = threadIdx.x;      // 0..63
    float val = 0.f;
    if (r < VOCAB) {
        int p = d >> 1;
        float div = __expf((float)(2 * p) * (-logf(10000.0f) / (float)D_));
        float ang = (float)r * div;
        val = (d & 1) ? cosf(ang) : sinf(ang);
        tab[r * D_ + d] = val;
    }
    tab_bf[r * D_ + d] = (bf16_t)val;
    if (r < 128) tabT_bf[d * 128 + r] = (bf16_t)val;
}

// ---------------------------------------------------------------------------
__global__ __launch_bounds__(256) void cast_f32_bf16(const float* __restrict__ src,
                                                     bf16_t* __restrict__ dst, int n4) {
    int i = blockIdx.x * 256 + threadIdx.x;
    if (i < n4) {
        float4 v = ((const float4*)src)[i];
        bf16x4 o = {(bf16_t)v.x, (bf16_t)v.y, (bf16_t)v.z, (bf16_t)v.w};
        ((bf16x4*)dst)[i] = o;
    }
}

// ---------------------------------------------------------------------------
// Fused QKV projection (m97 pattern). Writes Qbf/Kbf [B,NH,S,D] bf16 and
// vv [B,NH,S,D] f32 (V is transposed to [B,NH,D,S] bf16 by a separate kernel).
// ---------------------------------------------------------------------------
__global__ __launch_bounds__(256) void proj_mfma_kernel(
        const bf16_t* __restrict__ Abf,   // [2048][1024]
        const bf16_t* __restrict__ Wbf,   // [3072][1024]  (Wq;Wk;Wv)
        const float* __restrict__ bq, const float* __restrict__ bk,
        const float* __restrict__ bv,
        bf16_t* __restrict__ Qbf, bf16_t* __restrict__ Kbf, float* __restrict__ vv) {
    __shared__ __align__(16) bf16_t As[128 * 32];
    __shared__ __align__(16) bf16_t Bs[128 * 32];
    const int tid = threadIdx.x;
    const int w = tid >> 6, l = tid & 63;
    const int m0 = blockIdx.y * 128, n0 = blockIdx.x * 128;
    const int wm = w & 1, wn = w >> 1;

    f32x4 acc[4][4] = {};

    const int lrow = l >> 2;
    const int lcol = (l & 3) * 8;
    const int frow = l & 15;
    const int kq = (l >> 4) * 8;

    for (int kt = 0; kt < H_; kt += 32) {
#pragma unroll
        for (int t = 0; t < 2; t++) {
            int row = w * 32 + t * 16;
            const bf16_t* ga = Abf + (size_t)(m0 + row + lrow) * H_ + kt + lcol;
            const bf16_t* gb = Wbf + (size_t)(n0 + row + lrow) * H_ + kt + lcol;
            __builtin_amdgcn_global_load_lds(
                (const __attribute__((address_space(1))) void*)ga,
                (__attribute__((address_space(3))) void*)&As[row * 32], 16, 0, 0);
            __builtin_amdgcn_global_load_lds(
                (const __attribute__((address_space(1))) void*)gb,
                (__attribute__((address_space(3))) void*)&Bs[row * 32], 16, 0, 0);
        }
        __syncthreads();

        bf16x8 af[4], bfr[4];
#pragma unroll
        for (int im = 0; im < 4; im++)
            af[im] = *(const bf16x8*)&As[(wm * 64 + im * 16 + frow) * 32 + kq];
#pragma unroll
        for (int in = 0; in < 4; in++)
            bfr[in] = *(const bf16x8*)&Bs[(wn * 64 + in * 16 + frow) * 32 + kq];
#pragma unroll
        for (int im = 0; im < 4; im++)
#pragma unroll
            for (int in = 0; in < 4; in++)
                acc[im][in] = MFMA16(af[im], bfr[in], acc[im][in]);
        __syncthreads();
    }

    const int proj = n0 >> 10;
    const float* bias = proj == 0 ? bq : (proj == 1 ? bk : bv);
    bf16_t* bdst = proj == 0 ? Qbf : Kbf;
    const int cn = l & 15, cr4 = (l >> 4) * 4;
#pragma unroll
    for (int im = 0; im < 4; im++) {
#pragma unroll
        for (int in = 0; in < 4; in++) {
            int gn = n0 + wn * 64 + in * 16 + cn;
            int o = gn & 1023;
            int nn = o >> 6, dd = o & 63;
            float bsv = bias[o];
#pragma unroll
            for (int vr = 0; vr < 4; vr++) {
                int gm = m0 + wm * 64 + im * 16 + cr4 + vr;
                int bb = gm >> 10, ss = gm & 1023;
                size_t idx = (size_t)(((bb * NH_ + nn) << 10) + ss) * D_ + dd;
                float val = acc[im][in][vr] + bsv;
                if (proj == 2) vv[idx] = val;
                else bdst[idx] = (bf16_t)val;
            }
        }
    }
}

// ---------------------------------------------------------------------------
// vv [B,NH,S,D] f32 -> Vt [B,NH,D,S] bf16 (transpose via LDS tile)
// ---------------------------------------------------------------------------
__global__ __launch_bounds__(256) void transpose_v_kernel(const float* __restrict__ vv,
                                                          bf16_t* __restrict__ Vt) {
    __shared__ bf16_t T[64 * 72];
    const int bh = blockIdx.y, s0 = blockIdx.x * 64;
    const int t = threadIdx.x;
    const float* src = vv + ((size_t)bh * S_ + s0) * D_;
#pragma unroll
    for (int p = 0; p < 4; p++) {
        int sl = p * 16 + (t >> 4);
        int d4 = (t & 15) * 4;
        float4 x = *(const float4*)&src[(size_t)sl * D_ + d4];
        T[(d4 + 0) * 72 + sl] = (bf16_t)x.x;
        T[(d4 + 1) * 72 + sl] = (bf16_t)x.y;
        T[(d4 + 2) * 72 + sl] = (bf16_t)x.z;
        T[(d4 + 3) * 72 + sl] = (bf16_t)x.w;
    }
    __syncthreads();
    bf16_t* dst = Vt + (size_t)bh * D_ * S_;
    const int d = t >> 2, sc = (t & 3) * 16;
    *(bf16x8*)&dst[(size_t)d * S_ + s0 + sc]     = *(const bf16x8*)&T[d * 72 + sc];
    *(bf16x8*)&dst[(size_t)d * S_ + s0 + sc + 8] = *(const bf16x8*)&T[d * 72 + sc + 8];
}

// ---------------------------------------------------------------------------
// MFMA attention: one WAVE = 16 queries of one (b,h); block = 4 waves,
// no inter-wave sharing (LDS partitioned per wave, no __syncthreads in loop).
// ---------------------------------------------------------------------------
__global__ __launch_bounds__(256, 2) void attn_mfma_kernel(
        const bf16_t* __restrict__ Qbf, const bf16_t* __restrict__ Kbf,
        const bf16_t* __restrict__ Vt,  const bf16_t* __restrict__ tab_bf,
        const bf16_t* __restrict__ tabT_bf, const float* __restrict__ tab,
        const float* __restrict__ mask, float* __restrict__ out) {
    __shared__ __align__(16) bf16_t PlsA[4][16 * PSTR];    //  9.2 KB
    __shared__ __align__(16) bf16_t QrA[4][16 * QRSTR];    // 17.4 KB
    __shared__ __align__(16) bf16_t PbA[4][16 * QRSTR];    // 17.4 KB
    __shared__ float Ptail[4][16][2];                      //  0.5 KB
    __shared__ float SArr[4][16][3];                       //  0.8 KB

    const int tid = threadIdx.x;
    const int w = tid >> 6, l = tid & 63;
    const int lr = l & 15;          // m/n fragment index
    const int lk = (l >> 4) * 8;    // k fragment offset
    const int reg4 = (l >> 4) * 4;  // C-layout row base
    const int q0 = blockIdx.x * 64 + w * 16;
    const int h = blockIdx.y, b = blockIdx.z;
    const size_t bh = (size_t)(b * NH_ + h);
    const bf16_t* Qh = Qbf + bh * S_ * D_;
    const bf16_t* Kh = Kbf + bh * S_ * D_;
    const bf16_t* Vh = Vt + bh * D_ * S_;

    bf16_t* myP = PlsA[w];
    bf16_t* myQr = QrA[w];
    bf16_t* myPb = PbA[w];

    // zero Pb (dword writes) + Ptail
    for (int e = l; e < 16 * QRSTR / 2; e += 64) ((unsigned*)myPb)[e] = 0u;
    if (l < 16) { Ptail[w][l][0] = 0.f; Ptail[w][l][1] = 0.f; }

    // Q A-frags (persist in registers)
    bf16x8 af0 = *(const bf16x8*)&Qh[(size_t)(q0 + lr) * D_ + lk];
    bf16x8 af1 = *(const bf16x8*)&Qh[(size_t)(q0 + lr) * D_ + 32 + lk];

    // Qr[i][r] = q_i . tab[r]  via mfma (9 n-tiles covering r=0..128)
#pragma unroll
    for (int nt = 0; nt < 9; nt++) {
        f32x4 qa = {0.f, 0.f, 0.f, 0.f};
        const bf16_t* tb = tab_bf + (size_t)(nt * 16 + lr) * D_;
        bf16x8 b0 = *(const bf16x8*)&tb[lk];
        bf16x8 b1 = *(const bf16x8*)&tb[32 + lk];
        qa = MFMA16(af0, b0, qa);
        qa = MFMA16(af1, b1, qa);
        int col = nt * 16 + lr;
        if (col <= 128) {
#pragma unroll
            for (int r = 0; r < 4; r++) myQr[(reg4 + r) * QRSTR + col] = (bf16_t)qa[r];
        }
    }
    LGKM_FENCE();
    float QrLo[4], QrHi[4];
#pragma unroll
    for (int r = 0; r < 4; r++) {
        QrLo[r] = (float)myQr[(reg4 + r) * QRSTR + 0];
        QrHi[r] = (float)myQr[(reg4 + r) * QRSTR + 128];
    }

    f32x4 oacc[5] = {};   // 4 d-tiles + stats tile (col64=lsum, 65=plo_pure, 66=phi_pure)

    for (int kt = 0; kt < S_ / 64; kt++) {
        const int k0 = kt * 64;
        const bool allLo = (k0 + 63 - q0 <= -64);
        const bool allHi = (k0 - (q0 + 15) >= 64);
        const bool mixed = !(allLo || allHi);

        // S = Q K^T
        f32x4 sac[4] = {};
#pragma unroll
        for (int nt = 0; nt < 4; nt++) {
            const bf16_t* kb = Kh + (size_t)(k0 + nt * 16 + lr) * D_;
            bf16x8 b0 = *(const bf16x8*)&kb[lk];
            bf16x8 b1 = *(const bf16x8*)&kb[32 + lk];
            sac[nt] = MFMA16(af0, b0, sac[nt]);
            sac[nt] = MFMA16(af1, b1, sac[nt]);
        }

        // transform: rel add, exp, bucket bookkeeping, P -> LDS
#pragma unroll
        for (int nt = 0; nt < 4; nt++) {
            int gj = k0 + nt * 16 + lr;
            float mj = mask[b * S_ + gj];
#pragma unroll
            for (int r = 0; r < 4; r++) {
                int gi = q0 + reg4 + r;
                float rel;
                if (allLo) rel = QrLo[r];
                else if (allHi) rel = QrHi[r];
                else {
                    int off = gj - gi;
                    off = off < -64 ? -64 : (off > 64 ? 64 : off);
                    rel = (float)myQr[(reg4 + r) * QRSTR + off + 64];
                }
                float p = __expf((sac[nt][r] + rel) * 0.125f + mj);
                if (mixed) {
                    int off = gj - gi;
                    if (off <= -64)      atomicAdd(&Ptail[w][reg4 + r][0], p);
                    else if (off >= 64)  atomicAdd(&Ptail[w][reg4 + r][1], p);
                    else                 myPb[(reg4 + r) * QRSTR + off + 64] = (bf16_t)p;
                }
                myP[(reg4 + r) * PSTR + nt * 16 + lr] = (bf16_t)p;
            }
        }
        LGKM_FENCE();

        // ones/indicator B-frag for the stats tile
        float ov = (lr == 0) ? 1.f : (lr == 1) ? (allLo ? 1.f : 0.f)
                 : (lr == 2) ? (allHi ? 1.f : 0.f) : 0.f;
        bf16_t ob = (bf16_t)ov;
        bf16x8 onesf = {ob, ob, ob, ob, ob, ob, ob, ob};

        // O += P V  (A from own LDS rows)
        bf16x8 pa0 = *(const bf16x8*)&myP[lr * PSTR + lk];
        bf16x8 pa1 = *(const bf16x8*)&myP[lr * PSTR + 32 + lk];
#pragma unroll
        for (int nt = 0; nt < 4; nt++) {
            const bf16_t* vb = Vh + (size_t)(nt * 16 + lr) * S_ + k0;
            bf16x8 b0 = *(const bf16x8*)&vb[lk];
            bf16x8 b1 = *(const bf16x8*)&vb[32 + lk];
            oacc[nt] = MFMA16(pa0, b0, oacc[nt]);
            oacc[nt] = MFMA16(pa1, b1, oacc[nt]);
        }
        oacc[4] = MFMA16(pa0, onesf, oacc[4]);
        oacc[4] = MFMA16(pa1, onesf, oacc[4]);
    }

    // stats to LDS (cross-lane within wave)
    if (lr < 3) {
#pragma unroll
        for (int r = 0; r < 4; r++) SArr[w][reg4 + r][lr] = oacc[4][r];
    }

    // rel-value middle-bucket GEMM: O += Pb . tabT  (k = r in 0..127)
#pragma unroll
    for (int kc = 0; kc < 4; kc++) {
        bf16x8 pa = *(const bf16x8*)&myPb[lr * QRSTR + kc * 32 + lk];
#pragma unroll
        for (int nt = 0; nt < 4; nt++) {
            bf16x8 tb = *(const bf16x8*)&tabT_bf[(size_t)(nt * 16 + lr) * 128 + kc * 32 + lk];
            oacc[nt] = MFMA16(pa, tb, oacc[nt]);
        }
    }
    LGKM_FENCE();

    // combine: tails, normalize, store
#pragma unroll
    for (int r = 0; r < 4; r++) {
        int row = reg4 + r, gi = q0 + row;
        float lsum = SArr[w][row][0];
        float plo = SArr[w][row][1] + Ptail[w][row][0];
        float phi = SArr[w][row][2] + Ptail[w][row][1];
        float inv = 1.0f / lsum;
#pragma unroll
        for (int nt = 0; nt < 4; nt++) {
            int d = nt * 16 + lr;
            float o = oacc[nt][r] + plo * tab[d] + phi * tab[128 * D_ + d];
            out[((size_t)(b * S_ + gi) * NH_ + h) * D_ + d] = o * inv;
        }
    }
}

// ---------------------------------------------------------------------------
extern "C" void kernel_launch(void* const* d_in, const int* in_sizes, int n_in,
                              void* d_out, int out_size, void* d_ws, size_t ws_size,
                              hipStream_t stream) {
    const float* hidden = (const float*)d_in[0];
    const float* mask   = (const float*)d_in[1];
    const float* Wq     = (const float*)d_in[2];
    const float* bq     = (const float*)d_in[3];
    const float* Wk     = (const float*)d_in[4];
    const float* bk     = (const float*)d_in[5];
    const float* Wv     = (const float*)d_in[6];
    const float* bv     = (const float*)d_in[7];
    float* out = (float*)d_out;

    char* wsb = (char*)d_ws;
    bf16_t* Qbf    = (bf16_t*)(wsb);                                // 4 MB
    bf16_t* Kbf    = (bf16_t*)(wsb + (4u << 20));                   // 4 MB
    float*  vv     = (float*) (wsb + (8u << 20));                   // 8 MB
    bf16_t* Vt     = (bf16_t*)(wsb + (16u << 20));                  // 4 MB
    float*  tab    = (float*) (wsb + (20u << 20));                  // 33 KB
    bf16_t* tab_bf = (bf16_t*)(wsb + (20u << 20) + (64u << 10));    // 18.4 KB
    bf16_t* tabT   = (bf16_t*)(wsb + (20u << 20) + (96u << 10));    // 16 KB
    bf16_t* hidbf  = (bf16_t*)(wsb + (20u << 20) + (128u << 10));   // 4 MB
    bf16_t* wbf    = (bf16_t*)(wsb + (24u << 20) + (128u << 10));   // 6 MB

    const int NM = 1024 * 1024;

    build_tab_kernel<<<dim3(144), dim3(64), 0, stream>>>(tab, tab_bf, tabT);
    cast_f32_bf16<<<dim3((2 * NM / 4) / 256), dim3(256), 0, stream>>>(hidden, hidbf, 2 * NM / 4);
    cast_f32_bf16<<<dim3((NM / 4) / 256), dim3(256), 0, stream>>>(Wq, wbf, NM / 4);
    cast_f32_bf16<<<dim3((NM / 4) / 256), dim3(256), 0, stream>>>(Wk, wbf + NM, NM / 4);
    cast_f32_bf16<<<dim3((NM / 4) / 256), dim3(256), 0, stream>>>(Wv, wbf + 2 * NM, NM / 4);

    proj_mfma_kernel<<<dim3(3072 / 128, 2048 / 128), dim3(256), 0, stream>>>(
        hidbf, wbf, bq, bk, bv, Qbf, Kbf, vv);

    transpose_v_kernel<<<dim3(S_ / 64, B_ * NH_), dim3(256), 0, stream>>>(vv, Vt);

    attn_mfma_kernel<<<dim3(S_ / 64, NH_, B_), dim3(256), 0, stream>>>(
        Qbf, Kbf, Vt, tab_bf, tabT, tab, mask, out);
}

// Round 5
// 182.492 us; speedup vs baseline: 17.9593x; 1.1884x over previous
//
#include <hip/hip_runtime.h>
#include <hip/hip_bf16.h>
#include <math.h>

#define B_ 2
#define S_ 1024
#define H_ 1024
#define NH_ 16
#define D_ 64
#define VOCAB 129

#define PSTR 72     // P LDS row stride (bf16)
#define QRSTR 136   // Qr/Pb LDS row stride (bf16)

typedef __bf16 bf16_t;
typedef __bf16 bf16x8 __attribute__((ext_vector_type(8)));
typedef __bf16 bf16x4 __attribute__((ext_vector_type(4)));
typedef float f32x4 __attribute__((ext_vector_type(4)));

#define MFMA16(a, b, c) __builtin_amdgcn_mfma_f32_16x16x32_bf16(a, b, c, 0, 0, 0)
#define LGKM_FENCE() __asm__ volatile("s_waitcnt lgkmcnt(0)" ::: "memory")

// ---------------------------------------------------------------------------
__global__ void build_tab_kernel(float* __restrict__ tab, bf16_t* __restrict__ tab_bf,
                                 bf16_t* __restrict__ tabT_bf) {
    int r = blockIdx.x;       // 0..143
    int d = threadIdx.x;      // 0..63
    float val = 0.f;
    if (r < VOCAB) {
        int p = d >> 1;
        float div = __expf((float)(2 * p) * (-logf(10000.0f) / (float)D_));
        float ang = (float)r * div;
        val = (d & 1) ? cosf(ang) : sinf(ang);
        tab[r * D_ + d] = val;
    }
    tab_bf[r * D_ + d] = (bf16_t)val;
    if (r < 128) tabT_bf[d * 128 + r] = (bf16_t)val;
}

// ---------------------------------------------------------------------------
// One fused cast: hidden (512K float4) then Wq/Wk/Wv (256K float4 each).
// ---------------------------------------------------------------------------
__global__ __launch_bounds__(256) void cast_all_kernel(
        const float* __restrict__ hidden, const float* __restrict__ Wq,
        const float* __restrict__ Wk, const float* __restrict__ Wv,
        bf16_t* __restrict__ hidbf, bf16_t* __restrict__ wbf) {
    const int i = blockIdx.x * 256 + threadIdx.x;   // float4 index, < 1280K
    const int HID4 = 512 * 1024, W4 = 256 * 1024;
    const float* src;
    bf16_t* dst;
    int off;
    if (i < HID4)            { src = hidden; dst = hidbf;             off = i; }
    else if (i < HID4 + W4)  { src = Wq;     dst = wbf;               off = i - HID4; }
    else if (i < HID4 + 2*W4){ src = Wk;     dst = wbf + 1024*1024;   off = i - HID4 - W4; }
    else                     { src = Wv;     dst = wbf + 2*1024*1024; off = i - HID4 - 2*W4; }
    float4 v = ((const float4*)src)[off];
    bf16x4 o = {(bf16_t)v.x, (bf16_t)v.y, (bf16_t)v.z, (bf16_t)v.w};
    ((bf16x4*)dst)[off] = o;
}

// ---------------------------------------------------------------------------
// Fused QKV projection (m97 pattern). Q/K -> [B,NH,S,D] bf16;
// V -> Vt [B,NH,D,S] bf16 directly (transposed store, bf16x4 per lane).
// ---------------------------------------------------------------------------
__global__ __launch_bounds__(256) void proj_mfma_kernel(
        const bf16_t* __restrict__ Abf,   // [2048][1024]
        const bf16_t* __restrict__ Wbf,   // [3072][1024]  (Wq;Wk;Wv)
        const float* __restrict__ bq, const float* __restrict__ bk,
        const float* __restrict__ bv,
        bf16_t* __restrict__ Qbf, bf16_t* __restrict__ Kbf, bf16_t* __restrict__ Vt) {
    __shared__ __align__(16) bf16_t As[128 * 32];
    __shared__ __align__(16) bf16_t Bs[128 * 32];
    const int tid = threadIdx.x;
    const int w = tid >> 6, l = tid & 63;
    const int m0 = blockIdx.y * 128, n0 = blockIdx.x * 128;
    const int wm = w & 1, wn = w >> 1;

    f32x4 acc[4][4] = {};

    const int lrow = l >> 2;
    const int lcol = (l & 3) * 8;
    const int frow = l & 15;
    const int kq = (l >> 4) * 8;

    for (int kt = 0; kt < H_; kt += 32) {
#pragma unroll
        for (int t = 0; t < 2; t++) {
            int row = w * 32 + t * 16;
            const bf16_t* ga = Abf + (size_t)(m0 + row + lrow) * H_ + kt + lcol;
            const bf16_t* gb = Wbf + (size_t)(n0 + row + lrow) * H_ + kt + lcol;
            __builtin_amdgcn_global_load_lds(
                (const __attribute__((address_space(1))) void*)ga,
                (__attribute__((address_space(3))) void*)&As[row * 32], 16, 0, 0);
            __builtin_amdgcn_global_load_lds(
                (const __attribute__((address_space(1))) void*)gb,
                (__attribute__((address_space(3))) void*)&Bs[row * 32], 16, 0, 0);
        }
        __syncthreads();

        bf16x8 af[4], bfr[4];
#pragma unroll
        for (int im = 0; im < 4; im++)
            af[im] = *(const bf16x8*)&As[(wm * 64 + im * 16 + frow) * 32 + kq];
#pragma unroll
        for (int in = 0; in < 4; in++)
            bfr[in] = *(const bf16x8*)&Bs[(wn * 64 + in * 16 + frow) * 32 + kq];
#pragma unroll
        for (int im = 0; im < 4; im++)
#pragma unroll
            for (int in = 0; in < 4; in++)
                acc[im][in] = MFMA16(af[im], bfr[in], acc[im][in]);
        __syncthreads();
    }

    const int proj = n0 >> 10;
    const int cn = l & 15, cr4 = (l >> 4) * 4;
    if (proj == 2) {
        // V: transposed bf16x4 stores into Vt[B,NH,D,S]
#pragma unroll
        for (int im = 0; im < 4; im++) {
#pragma unroll
            for (int in = 0; in < 4; in++) {
                int gn = n0 + wn * 64 + in * 16 + cn;
                int o = gn & 1023;
                int nn = o >> 6, dd = o & 63;
                float bsv = bv[o];
                int gm0 = m0 + wm * 64 + im * 16 + cr4;
                int bb = gm0 >> 10, ss = gm0 & 1023;
                bf16x4 pv = {(bf16_t)(acc[im][in][0] + bsv), (bf16_t)(acc[im][in][1] + bsv),
                             (bf16_t)(acc[im][in][2] + bsv), (bf16_t)(acc[im][in][3] + bsv)};
                *(bf16x4*)&Vt[((size_t)(bb * NH_ + nn) * D_ + dd) * S_ + ss] = pv;
            }
        }
    } else {
        const float* bias = proj == 0 ? bq : bk;
        bf16_t* bdst = proj == 0 ? Qbf : Kbf;
#pragma unroll
        for (int im = 0; im < 4; im++) {
#pragma unroll
            for (int in = 0; in < 4; in++) {
                int gn = n0 + wn * 64 + in * 16 + cn;
                int o = gn & 1023;
                int nn = o >> 6, dd = o & 63;
                float bsv = bias[o];
#pragma unroll
                for (int vr = 0; vr < 4; vr++) {
                    int gm = m0 + wm * 64 + im * 16 + cr4 + vr;
                    int bb = gm >> 10, ss = gm & 1023;
                    bdst[(size_t)(((bb * NH_ + nn) << 10) + ss) * D_ + dd] =
                        (bf16_t)(acc[im][in][vr] + bsv);
                }
            }
        }
    }
}

// ---------------------------------------------------------------------------
// MFMA attention, software-pipelined: one wave = 16 queries; K-frags for tile
// kt+1 and V-frags/mask for tile kt issued at the top of each iteration.
// ---------------------------------------------------------------------------
__device__ __forceinline__ void load_kfrags(const bf16_t* __restrict__ Kh, int k0,
                                            int lr, int lk, bf16x8 (&kf)[8]) {
#pragma unroll
    for (int nt = 0; nt < 4; nt++) {
        const bf16_t* kb = Kh + (size_t)(k0 + nt * 16 + lr) * D_;
        kf[2 * nt]     = *(const bf16x8*)&kb[lk];
        kf[2 * nt + 1] = *(const bf16x8*)&kb[32 + lk];
    }
}

#define ATTN_TILE(KT, CUR, NXT, MCUR, MNXT) do {                                   \
    const int k0 = (KT) * 64;                                                      \
    const int ktn = (KT) < 15 ? (KT) + 1 : 15;                                     \
    load_kfrags(Kh, ktn * 64, lr, lk, NXT);                                        \
    _Pragma("unroll")                                                              \
    for (int nt = 0; nt < 4; nt++) MNXT[nt] = mrow[ktn * 64 + nt * 16 + lr];       \
    bf16x8 vf[8];                                                                  \
    _Pragma("unroll")                                                              \
    for (int nt = 0; nt < 4; nt++) {                                               \
        const bf16_t* vb = Vh + (size_t)(nt * 16 + lr) * S_ + k0;                  \
        vf[2 * nt]     = *(const bf16x8*)&vb[lk];                                  \
        vf[2 * nt + 1] = *(const bf16x8*)&vb[32 + lk];                             \
    }                                                                              \
    const bool allLo = (k0 + 63 - q0 <= -64);                                      \
    const bool allHi = (k0 - (q0 + 15) >= 64);                                     \
    const bool mixed = !(allLo || allHi);                                          \
    f32x4 sac[4] = {};                                                             \
    _Pragma("unroll")                                                              \
    for (int nt = 0; nt < 4; nt++) {                                               \
        sac[nt] = MFMA16(af0, CUR[2 * nt], sac[nt]);                               \
        sac[nt] = MFMA16(af1, CUR[2 * nt + 1], sac[nt]);                           \
    }                                                                              \
    _Pragma("unroll")                                                              \
    for (int nt = 0; nt < 4; nt++) {                                               \
        int gj = k0 + nt * 16 + lr;                                                \
        float mj = MCUR[nt];                                                       \
        _Pragma("unroll")                                                          \
        for (int r = 0; r < 4; r++) {                                              \
            int gi = q0 + reg4 + r;                                                \
            float rel;                                                             \
            if (allLo) rel = QrLo[r];                                              \
            else if (allHi) rel = QrHi[r];                                         \
            else {                                                                 \
                int off = gj - gi;                                                 \
                off = off < -64 ? -64 : (off > 64 ? 64 : off);                     \
                rel = (float)myQr[(reg4 + r) * QRSTR + off + 64];                  \
            }                                                                      \
            float p = __expf((sac[nt][r] + rel) * 0.125f + mj);                    \
            if (mixed) {                                                           \
                int off = gj - gi;                                                 \
                if (off <= -64)      atomicAdd(&Ptail[w][reg4 + r][0], p);         \
                else if (off >= 64)  atomicAdd(&Ptail[w][reg4 + r][1], p);         \
                else                 myPb[(reg4 + r) * QRSTR + off + 64] = (bf16_t)p; \
            }                                                                      \
            myP[(reg4 + r) * PSTR + nt * 16 + lr] = (bf16_t)p;                     \
        }                                                                          \
    }                                                                              \
    LGKM_FENCE();                                                                  \
    float ov = (lr == 0) ? 1.f : (lr == 1) ? (allLo ? 1.f : 0.f)                   \
             : (lr == 2) ? (allHi ? 1.f : 0.f) : 0.f;                              \
    bf16_t ob = (bf16_t)ov;                                                        \
    bf16x8 onesf = {ob, ob, ob, ob, ob, ob, ob, ob};                               \
    bf16x8 pa0 = *(const bf16x8*)&myP[lr * PSTR + lk];                             \
    bf16x8 pa1 = *(const bf16x8*)&myP[lr * PSTR + 32 + lk];                        \
    _Pragma("unroll")                                                              \
    for (int nt = 0; nt < 4; nt++) {                                               \
        oacc[nt] = MFMA16(pa0, vf[2 * nt], oacc[nt]);                              \
        oacc[nt] = MFMA16(pa1, vf[2 * nt + 1], oacc[nt]);                          \
    }                                                                              \
    oacc[4] = MFMA16(pa0, onesf, oacc[4]);                                         \
    oacc[4] = MFMA16(pa1, onesf, oacc[4]);                                         \
} while (0)

__global__ __launch_bounds__(256, 2) void attn_mfma_kernel(
        const bf16_t* __restrict__ Qbf, const bf16_t* __restrict__ Kbf,
        const bf16_t* __restrict__ Vt,  const bf16_t* __restrict__ tab_bf,
        const bf16_t* __restrict__ tabT_bf, const float* __restrict__ tab,
        const float* __restrict__ mask, float* __restrict__ out) {
    __shared__ __align__(16) bf16_t PlsA[4][16 * PSTR];
    __shared__ __align__(16) bf16_t QrA[4][16 * QRSTR];
    __shared__ __align__(16) bf16_t PbA[4][16 * QRSTR];
    __shared__ float Ptail[4][16][2];
    __shared__ float SArr[4][16][3];

    const int tid = threadIdx.x;
    const int w = tid >> 6, l = tid & 63;
    const int lr = l & 15;
    const int lk = (l >> 4) * 8;
    const int reg4 = (l >> 4) * 4;
    const int q0 = blockIdx.x * 64 + w * 16;
    const int h = blockIdx.y, b = blockIdx.z;
    const size_t bh = (size_t)(b * NH_ + h);
    const bf16_t* Qh = Qbf + bh * S_ * D_;
    const bf16_t* Kh = Kbf + bh * S_ * D_;
    const bf16_t* Vh = Vt + bh * D_ * S_;
    const float* mrow = mask + b * S_;

    bf16_t* myP = PlsA[w];
    bf16_t* myQr = QrA[w];
    bf16_t* myPb = PbA[w];

    for (int e = l; e < 16 * QRSTR / 2; e += 64) ((unsigned*)myPb)[e] = 0u;
    if (l < 16) { Ptail[w][l][0] = 0.f; Ptail[w][l][1] = 0.f; }

    bf16x8 af0 = *(const bf16x8*)&Qh[(size_t)(q0 + lr) * D_ + lk];
    bf16x8 af1 = *(const bf16x8*)&Qh[(size_t)(q0 + lr) * D_ + 32 + lk];

    // Qr[i][r] = q_i . tab[r]
#pragma unroll
    for (int nt = 0; nt < 9; nt++) {
        f32x4 qa = {0.f, 0.f, 0.f, 0.f};
        const bf16_t* tb = tab_bf + (size_t)(nt * 16 + lr) * D_;
        bf16x8 b0 = *(const bf16x8*)&tb[lk];
        bf16x8 b1 = *(const bf16x8*)&tb[32 + lk];
        qa = MFMA16(af0, b0, qa);
        qa = MFMA16(af1, b1, qa);
        int col = nt * 16 + lr;
        if (col <= 128) {
#pragma unroll
            for (int r = 0; r < 4; r++) myQr[(reg4 + r) * QRSTR + col] = (bf16_t)qa[r];
        }
    }
    LGKM_FENCE();
    float QrLo[4], QrHi[4];
#pragma unroll
    for (int r = 0; r < 4; r++) {
        QrLo[r] = (float)myQr[(reg4 + r) * QRSTR + 0];
        QrHi[r] = (float)myQr[(reg4 + r) * QRSTR + 128];
    }

    f32x4 oacc[5] = {};

    bf16x8 kfA[8], kfB[8];
    float mvA[4], mvB[4];
    load_kfrags(Kh, 0, lr, lk, kfA);
#pragma unroll
    for (int nt = 0; nt < 4; nt++) mvA[nt] = mrow[nt * 16 + lr];

    for (int kt = 0; kt < 16; kt += 2) {
        ATTN_TILE(kt, kfA, kfB, mvA, mvB);
        ATTN_TILE(kt + 1, kfB, kfA, mvB, mvA);
    }

    if (lr < 3) {
#pragma unroll
        for (int r = 0; r < 4; r++) SArr[w][reg4 + r][lr] = oacc[4][r];
    }

    // O += Pb . tabT
#pragma unroll
    for (int kc = 0; kc < 4; kc++) {
        bf16x8 pa = *(const bf16x8*)&myPb[lr * QRSTR + kc * 32 + lk];
#pragma unroll
        for (int nt = 0; nt < 4; nt++) {
            bf16x8 tb = *(const bf16x8*)&tabT_bf[(size_t)(nt * 16 + lr) * 128 + kc * 32 + lk];
            oacc[nt] = MFMA16(pa, tb, oacc[nt]);
        }
    }
    LGKM_FENCE();

#pragma unroll
    for (int r = 0; r < 4; r++) {
        int row = reg4 + r, gi = q0 + row;
        float lsum = SArr[w][row][0];
        float plo = SArr[w][row][1] + Ptail[w][row][0];
        float phi = SArr[w][row][2] + Ptail[w][row][1];
        float inv = 1.0f / lsum;
#pragma unroll
        for (int nt = 0; nt < 4; nt++) {
            int d = nt * 16 + lr;
            float o = oacc[nt][r] + plo * tab[d] + phi * tab[128 * D_ + d];
            out[((size_t)(b * S_ + gi) * NH_ + h) * D_ + d] = o * inv;
        }
    }
}

// ---------------------------------------------------------------------------
extern "C" void kernel_launch(void* const* d_in, const int* in_sizes, int n_in,
                              void* d_out, int out_size, void* d_ws, size_t ws_size,
                              hipStream_t stream) {
    const float* hidden = (const float*)d_in[0];
    const float* mask   = (const float*)d_in[1];
    const float* Wq     = (const float*)d_in[2];
    const float* bq     = (const float*)d_in[3];
    const float* Wk     = (const float*)d_in[4];
    const float* bk     = (const float*)d_in[5];
    const float* Wv     = (const float*)d_in[6];
    const float* bv     = (const float*)d_in[7];
    float* out = (float*)d_out;

    char* wsb = (char*)d_ws;
    bf16_t* Qbf    = (bf16_t*)(wsb);                                // 4 MB
    bf16_t* Kbf    = (bf16_t*)(wsb + (4u << 20));                   // 4 MB
    bf16_t* Vt     = (bf16_t*)(wsb + (8u << 20));                   // 4 MB
    float*  tab    = (float*) (wsb + (12u << 20));                  // 33 KB
    bf16_t* tab_bf = (bf16_t*)(wsb + (12u << 20) + (64u << 10));    // 18.4 KB
    bf16_t* tabT   = (bf16_t*)(wsb + (12u << 20) + (96u << 10));    // 16 KB
    bf16_t* hidbf  = (bf16_t*)(wsb + (12u << 20) + (128u << 10));   // 4 MB
    bf16_t* wbf    = (bf16_t*)(wsb + (16u << 20) + (128u << 10));   // 6 MB

    build_tab_kernel<<<dim3(144), dim3(64), 0, stream>>>(tab, tab_bf, tabT);
    cast_all_kernel<<<dim3(5120), dim3(256), 0, stream>>>(hidden, Wq, Wk, Wv, hidbf, wbf);

    proj_mfma_kernel<<<dim3(3072 / 128, 2048 / 128), dim3(256), 0, stream>>>(
        hidbf, wbf, bq, bk, bv, Qbf, Kbf, Vt);

    attn_mfma_kernel<<<dim3(S_ / 64, NH_, B_), dim3(256), 0, stream>>>(
        Qbf, Kbf, Vt, tab_bf, tabT, tab, mask, out);
}

// Round 6
// 181.068 us; speedup vs baseline: 18.1006x; 1.0079x over previous
//
#include <hip/hip_runtime.h>
#include <hip/hip_bf16.h>
#include <math.h>

#define B_ 2
#define S_ 1024
#define H_ 1024
#define NH_ 16
#define D_ 64
#define VOCAB 129

#define PSTR 72     // P LDS row stride (bf16)
#define QRSTR 136   // Qr/Pb LDS row stride (bf16)

typedef __bf16 bf16_t;
typedef __bf16 bf16x8 __attribute__((ext_vector_type(8)));
typedef __bf16 bf16x4 __attribute__((ext_vector_type(4)));
typedef float f32x4 __attribute__((ext_vector_type(4)));

#define MFMA16(a, b, c) __builtin_amdgcn_mfma_f32_16x16x32_bf16(a, b, c, 0, 0, 0)
#define LGKM_FENCE() __asm__ volatile("s_waitcnt lgkmcnt(0)" ::: "memory")

// ---------------------------------------------------------------------------
__global__ void build_tab_kernel(float* __restrict__ tab, bf16_t* __restrict__ tab_bf,
                                 bf16_t* __restrict__ tabT_bf) {
    int r = blockIdx.x;       // 0..143
    int d = threadIdx.x;      // 0..63
    float val = 0.f;
    if (r < VOCAB) {
        int p = d >> 1;
        float div = __expf((float)(2 * p) * (-logf(10000.0f) / (float)D_));
        float ang = (float)r * div;
        val = (d & 1) ? cosf(ang) : sinf(ang);
        tab[r * D_ + d] = val;
    }
    tab_bf[r * D_ + d] = (bf16_t)val;
    if (r < 128) tabT_bf[d * 128 + r] = (bf16_t)val;
}

// ---------------------------------------------------------------------------
__global__ __launch_bounds__(256) void cast_all_kernel(
        const float* __restrict__ hidden, const float* __restrict__ Wq,
        const float* __restrict__ Wk, const float* __restrict__ Wv,
        bf16_t* __restrict__ hidbf, bf16_t* __restrict__ wbf) {
    const int i = blockIdx.x * 256 + threadIdx.x;   // float4 index, < 1280K
    const int HID4 = 512 * 1024, W4 = 256 * 1024;
    const float* src;
    bf16_t* dst;
    int off;
    if (i < HID4)            { src = hidden; dst = hidbf;             off = i; }
    else if (i < HID4 + W4)  { src = Wq;     dst = wbf;               off = i - HID4; }
    else if (i < HID4 + 2*W4){ src = Wk;     dst = wbf + 1024*1024;   off = i - HID4 - W4; }
    else                     { src = Wv;     dst = wbf + 2*1024*1024; off = i - HID4 - 2*W4; }
    float4 v = ((const float4*)src)[off];
    bf16x4 o = {(bf16_t)v.x, (bf16_t)v.y, (bf16_t)v.z, (bf16_t)v.w};
    ((bf16x4*)dst)[off] = o;
}

// ---------------------------------------------------------------------------
// Fused QKV projection (m97 pattern) with LDS-staged coalesced epilogue.
// Q/K -> [B,NH,S,D] bf16;  V -> Vt [B,NH,D,S] bf16.
// ---------------------------------------------------------------------------
__global__ __launch_bounds__(256) void proj_mfma_kernel(
        const bf16_t* __restrict__ Abf,   // [2048][1024]
        const bf16_t* __restrict__ Wbf,   // [3072][1024]  (Wq;Wk;Wv)
        const float* __restrict__ bq, const float* __restrict__ bk,
        const float* __restrict__ bv,
        bf16_t* __restrict__ Qbf, bf16_t* __restrict__ Kbf, bf16_t* __restrict__ Vt) {
    __shared__ __align__(16) bf16_t As[128 * 32];
    __shared__ __align__(16) bf16_t Bs[128 * 32];
    __shared__ __align__(16) bf16_t Es[128 * 72];   // 18.4 KB epilogue staging
    const int tid = threadIdx.x;
    const int w = tid >> 6, l = tid & 63;
    const int m0 = blockIdx.y * 128, n0 = blockIdx.x * 128;
    const int wm = w & 1, wn = w >> 1;

    f32x4 acc[4][4] = {};

    const int lrow = l >> 2;
    const int lcol = (l & 3) * 8;
    const int frow = l & 15;
    const int kq = (l >> 4) * 8;

    for (int kt = 0; kt < H_; kt += 32) {
#pragma unroll
        for (int t = 0; t < 2; t++) {
            int row = w * 32 + t * 16;
            const bf16_t* ga = Abf + (size_t)(m0 + row + lrow) * H_ + kt + lcol;
            const bf16_t* gb = Wbf + (size_t)(n0 + row + lrow) * H_ + kt + lcol;
            __builtin_amdgcn_global_load_lds(
                (const __attribute__((address_space(1))) void*)ga,
                (__attribute__((address_space(3))) void*)&As[row * 32], 16, 0, 0);
            __builtin_amdgcn_global_load_lds(
                (const __attribute__((address_space(1))) void*)gb,
                (__attribute__((address_space(3))) void*)&Bs[row * 32], 16, 0, 0);
        }
        __syncthreads();

        bf16x8 af[4], bfr[4];
#pragma unroll
        for (int im = 0; im < 4; im++)
            af[im] = *(const bf16x8*)&As[(wm * 64 + im * 16 + frow) * 32 + kq];
#pragma unroll
        for (int in = 0; in < 4; in++)
            bfr[in] = *(const bf16x8*)&Bs[(wn * 64 + in * 16 + frow) * 32 + kq];
#pragma unroll
        for (int im = 0; im < 4; im++)
#pragma unroll
            for (int in = 0; in < 4; in++)
                acc[im][in] = MFMA16(af[im], bfr[in], acc[im][in]);
        __syncthreads();
    }

    const int proj = n0 >> 10;
    const int cn = l & 15, cr4 = (l >> 4) * 4;
    const int bb = m0 >> 10, mrem = m0 & 1023;

    if (proj < 2) {
        const float* bias = proj == 0 ? bq : bk;
        bf16_t* bdst = proj == 0 ? Qbf : Kbf;
        for (int hh = 0; hh < 2; hh++) {
            __syncthreads();
            if (wn == hh) {
#pragma unroll
                for (int im = 0; im < 4; im++) {
#pragma unroll
                    for (int in = 0; in < 4; in++) {
                        int nl = in * 16 + cn;
                        float bsv = bias[(n0 & 1023) + hh * 64 + nl];
                        int ml = wm * 64 + im * 16 + cr4;
#pragma unroll
                        for (int vr = 0; vr < 4; vr++)
                            Es[(ml + vr) * 72 + nl] = (bf16_t)(acc[im][in][vr] + bsv);
                    }
                }
            }
            __syncthreads();
            int nn = ((n0 & 1023) + hh * 64) >> 6;
            bf16_t* base = bdst + (size_t)(bb * NH_ + nn) * S_ * D_ + (size_t)mrem * D_;
#pragma unroll
            for (int t = 0; t < 4; t++) {
                int c = tid + t * 256;          // 0..1023 = 128 rows x 8 chunks
                int ml = c >> 3, c8 = (c & 7) * 8;
                *(bf16x8*)&base[(size_t)ml * D_ + c8] = *(const bf16x8*)&Es[ml * 72 + c8];
            }
        }
    } else {
        bf16_t* EsV = Es;                        // [64][136]
        for (int hh = 0; hh < 2; hh++) {
            __syncthreads();
            if (wn == hh) {
#pragma unroll
                for (int im = 0; im < 4; im++) {
#pragma unroll
                    for (int in = 0; in < 4; in++) {
                        int nl = in * 16 + cn;   // dd
                        float bsv = bv[(n0 & 1023) + hh * 64 + nl];
                        int ml = wm * 64 + im * 16 + cr4;
                        bf16x4 pv = {(bf16_t)(acc[im][in][0] + bsv),
                                     (bf16_t)(acc[im][in][1] + bsv),
                                     (bf16_t)(acc[im][in][2] + bsv),
                                     (bf16_t)(acc[im][in][3] + bsv)};
                        *(bf16x4*)&EsV[nl * 136 + ml] = pv;
                    }
                }
            }
            __syncthreads();
            int nn = ((n0 & 1023) + hh * 64) >> 6;
            bf16_t* base = Vt + (size_t)(bb * NH_ + nn) * D_ * S_ + mrem;
#pragma unroll
            for (int t = 0; t < 4; t++) {
                int c = tid + t * 256;          // 0..1023 = 64 rows x 16 chunks
                int dd = c >> 4, s8 = (c & 15) * 8;
                *(bf16x8*)&base[(size_t)dd * S_ + s8] = *(const bf16x8*)&EsV[dd * 136 + s8];
            }
        }
    }
}

// ---------------------------------------------------------------------------
// MFMA attention, K-split: block = 16 queries of one (b,h); wave w covers
// keys [w*256, w*256+256). Grid 2048 blocks (1D, head = gid&31 for XCD/L2
// locality). Partial O / stats combined via LDS at the end.
// ---------------------------------------------------------------------------
__global__ __launch_bounds__(256, 4) void attn_mfma_kernel(
        const bf16_t* __restrict__ Qbf, const bf16_t* __restrict__ Kbf,
        const bf16_t* __restrict__ Vt,  const bf16_t* __restrict__ tab_bf,
        const bf16_t* __restrict__ tabT_bf, const float* __restrict__ tab,
        const float* __restrict__ mask, float* __restrict__ out) {
    __shared__ __align__(16) bf16_t PlsA[4][16 * PSTR];   //  9.2 KB
    __shared__ __align__(16) bf16_t Qr[16 * QRSTR];       //  4.3 KB (block-shared)
    __shared__ __align__(16) bf16_t Pb[16 * QRSTR];       //  4.3 KB (block-shared)
    __shared__ float Ptail[16][2];                        //  0.13 KB
    __shared__ float SArr[4][16][3];                      //  0.8 KB
    __shared__ float Osh[4][16][68];                      // 17.4 KB

    const int tid = threadIdx.x;
    const int w = tid >> 6, l = tid & 63;
    const int lr = l & 15;
    const int lk = (l >> 4) * 8;
    const int reg4 = (l >> 4) * 4;

    const int gid = blockIdx.x;
    const int hl = gid & 31;            // head-linear: same head -> same XCD
    const int qblk = gid >> 5;
    const int b = hl >> 4, h = hl & 15;
    const int q0 = qblk * 16;

    const size_t bh = (size_t)(b * NH_ + h);
    const bf16_t* Qh = Qbf + bh * S_ * D_;
    const bf16_t* Kh = Kbf + bh * S_ * D_;
    const bf16_t* Vh = Vt + bh * D_ * S_;
    const float* mrow = mask + b * S_;
    bf16_t* myP = PlsA[w];

    // zero Pb + Ptail
    for (int e = tid; e < 16 * QRSTR / 2; e += 256) ((unsigned*)Pb)[e] = 0u;
    if (tid < 16) { Ptail[tid][0] = 0.f; Ptail[tid][1] = 0.f; }

    // Q A-frags (shared across waves; same addresses -> L1 hits)
    bf16x8 af0 = *(const bf16x8*)&Qh[(size_t)(q0 + lr) * D_ + lk];
    bf16x8 af1 = *(const bf16x8*)&Qh[(size_t)(q0 + lr) * D_ + 32 + lk];

    // Qr[i][r] = q_i . tab[r], n-tiles split across waves
    for (int nt = w; nt < 9; nt += 4) {
        f32x4 qa = {0.f, 0.f, 0.f, 0.f};
        const bf16_t* tb = tab_bf + (size_t)(nt * 16 + lr) * D_;
        qa = MFMA16(af0, *(const bf16x8*)&tb[lk], qa);
        qa = MFMA16(af1, *(const bf16x8*)&tb[32 + lk], qa);
        int col = nt * 16 + lr;
        if (col <= 128) {
#pragma unroll
            for (int r = 0; r < 4; r++) Qr[(reg4 + r) * QRSTR + col] = (bf16_t)qa[r];
        }
    }
    __syncthreads();

    float QrLo[4], QrHi[4];
#pragma unroll
    for (int r = 0; r < 4; r++) {
        QrLo[r] = (float)Qr[(reg4 + r) * QRSTR + 0];
        QrHi[r] = (float)Qr[(reg4 + r) * QRSTR + 128];
    }

    f32x4 oacc[5] = {};   // 4 d-tiles + stats (col0=lsum, col1=plo_pure, col2=phi_pure)
    const int kbase = w * 256;

    for (int kt = 0; kt < 4; kt++) {
        const int k0 = kbase + kt * 64;
        const bool allLo = (k0 + 63 - q0 <= -64);
        const bool allHi = (k0 - (q0 + 15) >= 64);
        const bool mixed = !(allLo || allHi);

        // mask
        float mj[4];
#pragma unroll
        for (int nt = 0; nt < 4; nt++) mj[nt] = mrow[k0 + nt * 16 + lr];

        // S = Q K^T (two k-halves, kf reused to cap liveness)
        f32x4 sac[4] = {};
        {
            bf16x8 kf[4];
#pragma unroll
            for (int nt = 0; nt < 4; nt++)
                kf[nt] = *(const bf16x8*)&Kh[(size_t)(k0 + nt * 16 + lr) * D_ + lk];
#pragma unroll
            for (int nt = 0; nt < 4; nt++) sac[nt] = MFMA16(af0, kf[nt], sac[nt]);
#pragma unroll
            for (int nt = 0; nt < 4; nt++)
                kf[nt] = *(const bf16x8*)&Kh[(size_t)(k0 + nt * 16 + lr) * D_ + 32 + lk];
#pragma unroll
            for (int nt = 0; nt < 4; nt++) sac[nt] = MFMA16(af1, kf[nt], sac[nt]);
        }

        // prefetch V (both k-halves) before the transform to cover latency
        bf16x8 vf[8];
#pragma unroll
        for (int nt = 0; nt < 4; nt++) {
            const bf16_t* vb = Vh + (size_t)(nt * 16 + lr) * S_ + k0;
            vf[2 * nt]     = *(const bf16x8*)&vb[lk];
            vf[2 * nt + 1] = *(const bf16x8*)&vb[32 + lk];
        }

        // transform: rel add, exp, bucket bookkeeping, P -> LDS
#pragma unroll
        for (int nt = 0; nt < 4; nt++) {
            int gj = k0 + nt * 16 + lr;
#pragma unroll
            for (int r = 0; r < 4; r++) {
                int gi = q0 + reg4 + r;
                float rel;
                if (allLo) rel = QrLo[r];
                else if (allHi) rel = QrHi[r];
                else {
                    int off = gj - gi;
                    off = off < -64 ? -64 : (off > 64 ? 64 : off);
                    rel = (float)Qr[(reg4 + r) * QRSTR + off + 64];
                }
                float p = __expf((sac[nt][r] + rel) * 0.125f + mj[nt]);
                if (mixed) {
                    int off = gj - gi;
                    if (off <= -64)      atomicAdd(&Ptail[reg4 + r][0], p);
                    else if (off >= 64)  atomicAdd(&Ptail[reg4 + r][1], p);
                    else                 Pb[(reg4 + r) * QRSTR + off + 64] = (bf16_t)p;
                }
                myP[(reg4 + r) * PSTR + nt * 16 + lr] = (bf16_t)p;
            }
        }
        LGKM_FENCE();

        float ov = (lr == 0) ? 1.f : (lr == 1) ? (allLo ? 1.f : 0.f)
                 : (lr == 2) ? (allHi ? 1.f : 0.f) : 0.f;
        bf16_t ob = (bf16_t)ov;
        bf16x8 onesf = {ob, ob, ob, ob, ob, ob, ob, ob};

        bf16x8 pa0 = *(const bf16x8*)&myP[lr * PSTR + lk];
        bf16x8 pa1 = *(const bf16x8*)&myP[lr * PSTR + 32 + lk];
#pragma unroll
        for (int nt = 0; nt < 4; nt++) {
            oacc[nt] = MFMA16(pa0, vf[2 * nt], oacc[nt]);
            oacc[nt] = MFMA16(pa1, vf[2 * nt + 1], oacc[nt]);
        }
        oacc[4] = MFMA16(pa0, onesf, oacc[4]);
        oacc[4] = MFMA16(pa1, onesf, oacc[4]);
    }

    // partials -> LDS
    if (lr < 3) {
#pragma unroll
        for (int r = 0; r < 4; r++) SArr[w][reg4 + r][lr] = oacc[4][r];
    }
#pragma unroll
    for (int nt = 0; nt < 4; nt++)
#pragma unroll
        for (int r = 0; r < 4; r++) Osh[w][reg4 + r][nt * 16 + lr] = oacc[nt][r];
    __syncthreads();

    // wave w owns d-tile w: sum partials, add rel-value GEMM, tails, store
    f32x4 c = {};
#pragma unroll
    for (int r = 0; r < 4; r++)
        c[r] = Osh[0][reg4 + r][w * 16 + lr] + Osh[1][reg4 + r][w * 16 + lr] +
               Osh[2][reg4 + r][w * 16 + lr] + Osh[3][reg4 + r][w * 16 + lr];
#pragma unroll
    for (int kc = 0; kc < 4; kc++) {
        bf16x8 pa = *(const bf16x8*)&Pb[lr * QRSTR + kc * 32 + lk];
        bf16x8 tb = *(const bf16x8*)&tabT_bf[(size_t)(w * 16 + lr) * 128 + kc * 32 + lk];
        c = MFMA16(pa, tb, c);
    }

#pragma unroll
    for (int r = 0; r < 4; r++) {
        int row = reg4 + r, gi = q0 + row;
        float ls  = SArr[0][row][0] + SArr[1][row][0] + SArr[2][row][0] + SArr[3][row][0];
        float plo = SArr[0][row][1] + SArr[1][row][1] + SArr[2][row][1] + SArr[3][row][1]
                  + Ptail[row][0];
        float phi = SArr[0][row][2] + SArr[1][row][2] + SArr[2][row][2] + SArr[3][row][2]
                  + Ptail[row][1];
        int d = w * 16 + lr;
        float o = c[r] + plo * tab[d] + phi * tab[128 * D_ + d];
        out[((size_t)(b * S_ + gi) * NH_ + h) * D_ + d] = o / ls;
    }
}

// ---------------------------------------------------------------------------
extern "C" void kernel_launch(void* const* d_in, const int* in_sizes, int n_in,
                              void* d_out, int out_size, void* d_ws, size_t ws_size,
                              hipStream_t stream) {
    const float* hidden = (const float*)d_in[0];
    const float* mask   = (const float*)d_in[1];
    const float* Wq     = (const float*)d_in[2];
    const float* bq     = (const float*)d_in[3];
    const float* Wk     = (const float*)d_in[4];
    const float* bk     = (const float*)d_in[5];
    const float* Wv     = (const float*)d_in[6];
    const float* bv     = (const float*)d_in[7];
    float* out = (float*)d_out;

    char* wsb = (char*)d_ws;
    bf16_t* Qbf    = (bf16_t*)(wsb);                                // 4 MB
    bf16_t* Kbf    = (bf16_t*)(wsb + (4u << 20));                   // 4 MB
    bf16_t* Vt     = (bf16_t*)(wsb + (8u << 20));                   // 4 MB
    float*  tab    = (float*) (wsb + (12u << 20));                  // 33 KB
    bf16_t* tab_bf = (bf16_t*)(wsb + (12u << 20) + (64u << 10));    // 18.4 KB
    bf16_t* tabT   = (bf16_t*)(wsb + (12u << 20) + (96u << 10));    // 16 KB
    bf16_t* hidbf  = (bf16_t*)(wsb + (12u << 20) + (128u << 10));   // 4 MB
    bf16_t* wbf    = (bf16_t*)(wsb + (16u << 20) + (128u << 10));   // 6 MB

    build_tab_kernel<<<dim3(144), dim3(64), 0, stream>>>(tab, tab_bf, tabT);
    cast_all_kernel<<<dim3(5120), dim3(256), 0, stream>>>(hidden, Wq, Wk, Wv, hidbf, wbf);

    proj_mfma_kernel<<<dim3(3072 / 128, 2048 / 128), dim3(256), 0, stream>>>(
        hidbf, wbf, bq, bk, bv, Qbf, Kbf, Vt);

    attn_mfma_kernel<<<dim3((S_ / 16) * NH_ * B_), dim3(256), 0, stream>>>(
        Qbf, Kbf, Vt, tab_bf, tabT, tab, mask, out);
}